// Round 5
// baseline (120.880 us; speedup 1.0000x reference)
//
#include <hip/hip_runtime.h>
#include <math.h>

#define NPOS 512
#define DIM  512
#define NB   1024
#define EPSV 1e-5f
#define COS_EPS 1e-8f

// ws float offsets
#define OFF_INV 0                      // [1024] inv norms, allv order [pos;neg]
#define OFF_T1  1024                   // [512]  pos . w1
#define OFF_T2  1536                   // [1024] allv . w2
#define OFF_P   2560                   // partial buffers
#define PSZ     (NPOS * NB)            // 524288 floats each
// S partial z (z=0..7): ws + OFF_P + z*PSZ        (raw dot, cols = allv m)
// T partial z (z=0..7): ws + OFF_P + (8+z)*PSZ    (t3)

__device__ __forceinline__ float softplus_f(float x) {
    return fmaxf(x, 0.f) + __logf(1.f + __expf(-fabsf(x)));
}

// ---------------- Kernel 1: norms + t1 + t2 + zero out ----------------
__global__ __launch_bounds__(256) void prep_kernel(
    const float* __restrict__ pos, const float* __restrict__ neg,
    const float* __restrict__ w, float* __restrict__ ws, float* __restrict__ out)
{
    int gtid = blockIdx.x * 256 + threadIdx.x;
    if (gtid == 0) out[0] = 0.f;
    int row  = gtid >> 6;     // one wave per row, 1024 rows (allv order)
    int lane = threadIdx.x & 63;
    if (row >= NB) return;
    bool is_pos = row < NPOS;
    const float* r = is_pos ? pos + row * DIM : neg + (row - NPOS) * DIM;

    const float4* r4  = (const float4*)r + lane * 2;
    const float4* w14 = (const float4*)(w) + lane * 2;
    const float4* w24 = (const float4*)(w + DIM) + lane * 2;
    float4 a0 = r4[0],  a1 = r4[1];
    float4 u0 = w14[0], u1 = w14[1];
    float4 v0 = w24[0], v1 = w24[1];

    float ss  = a0.x*a0.x + a0.y*a0.y + a0.z*a0.z + a0.w*a0.w
              + a1.x*a1.x + a1.y*a1.y + a1.z*a1.z + a1.w*a1.w;
    float dw1 = a0.x*u0.x + a0.y*u0.y + a0.z*u0.z + a0.w*u0.w
              + a1.x*u1.x + a1.y*u1.y + a1.z*u1.z + a1.w*u1.w;
    float dw2 = a0.x*v0.x + a0.y*v0.y + a0.z*v0.z + a0.w*v0.w
              + a1.x*v1.x + a1.y*v1.y + a1.z*v1.z + a1.w*v1.w;

    #pragma unroll
    for (int off = 32; off; off >>= 1) {
        ss  += __shfl_xor(ss, off);
        dw1 += __shfl_xor(dw1, off);
        dw2 += __shfl_xor(dw2, off);
    }
    if (lane == 0) {
        float inv = 1.f / fmaxf(sqrtf(ss), COS_EPS);
        ws[OFF_INV + row] = inv;
        ws[OFF_T2 + row]  = dw2;
        if (is_pos) ws[OFF_T1 + row] = dw1;
    }
}

// ---------------- Kernel 2: fused cos + t3 partials ----------------
// 128n x 128m tile, 8x8 per thread (rows ti+16r, cols tj+16s), BK=64,
// k-split(8) over grid z. grid (8,4,8) = 256 blocks = 1 block/CU.
// LDS demand is 0.5x VALU demand -> VALU-bound by design.
__global__ __launch_bounds__(256, 1) void fused_kernel(
    const float* __restrict__ pos, const float* __restrict__ neg,
    const float* __restrict__ w, float* __restrict__ ws)
{
    __shared__ __align__(16) float As[128][68];
    __shared__ __align__(16) float Bs[128][68];

    const int tid = threadIdx.x;
    const int m0 = blockIdx.x * 128;
    const int n0 = blockIdx.y * 128;
    const int z  = blockIdx.z;

    const float* Asrc = pos + (size_t)n0 * DIM + z * 64;
    const float* Bsrc = ((m0 < NPOS) ? (pos + (size_t)m0 * DIM)
                                     : (neg + (size_t)(m0 - NPOS) * DIM)) + z * 64;
    const float* w3 = w + 2 * DIM + z * 64;

    // staging: 16 threads x 4 floats cover one 16-row x 64-col slab
    const int lr = tid >> 4;        // 0..15
    const int lc = (tid & 15) << 2; // 0..60
    #pragma unroll
    for (int q = 0; q < 8; ++q) {
        int row = lr + 16 * q;
        *(float4*)&As[row][lc] = *(const float4*)(Asrc + (size_t)row * DIM + lc);
        *(float4*)&Bs[row][lc] = *(const float4*)(Bsrc + (size_t)row * DIM + lc);
    }
    __syncthreads();

    const int ti = tid >> 4;   // 0..15 (within wave: 4 distinct -> broadcast)
    const int tj = tid & 15;   // 0..15

    float c[8][8] = {{0.f}};
    float t[8][8] = {{0.f}};

    #pragma unroll 2
    for (int k = 0; k < 64; k += 4) {
        const float4 wv = *(const float4*)(w3 + k);   // wave-uniform
        float4 bv[8];
        #pragma unroll
        for (int s = 0; s < 8; ++s) bv[s] = *(const float4*)&Bs[tj + 16 * s][k];
        #pragma unroll
        for (int r = 0; r < 8; ++r) {
            const float4 av = *(const float4*)&As[ti + 16 * r][k];
            #pragma unroll
            for (int s = 0; s < 8; ++s) {
                c[r][s] = fmaf(av.x, bv[s].x, c[r][s]);
                c[r][s] = fmaf(av.y, bv[s].y, c[r][s]);
                c[r][s] = fmaf(av.z, bv[s].z, c[r][s]);
                c[r][s] = fmaf(av.w, bv[s].w, c[r][s]);
                t[r][s] = fmaf(fabsf(av.x - bv[s].x), wv.x, t[r][s]);
                t[r][s] = fmaf(fabsf(av.y - bv[s].y), wv.y, t[r][s]);
                t[r][s] = fmaf(fabsf(av.z - bv[s].z), wv.z, t[r][s]);
                t[r][s] = fmaf(fabsf(av.w - bv[s].w), wv.w, t[r][s]);
            }
        }
    }

    float* Sp = ws + OFF_P + (size_t)z * PSZ;
    float* Tp = ws + OFF_P + (size_t)(8 + z) * PSZ;
    #pragma unroll
    for (int r = 0; r < 8; ++r) {
        int n = n0 + ti + 16 * r;
        #pragma unroll
        for (int s = 0; s < 8; ++s) {
            int m = m0 + tj + 16 * s;
            Sp[(size_t)n * NB + m] = c[r][s];
            Tp[(size_t)n * NB + m] = t[r][s];
        }
    }
}

// ---------------- Kernel 3: combine partials + closs + BCE ----------------
// 512 blocks, one n-row per block; 4 waves split the m range (256 m each).
// waves 2,3 own neg cols (deno); cross-wave eneg via LDS.
__global__ __launch_bounds__(256) void finish_kernel(
    const float* __restrict__ lb, const float* __restrict__ ws, float* __restrict__ out)
{
    __shared__ float eneg_s[4];
    __shared__ float red[4];

    const int n  = blockIdx.x;
    const int wv = threadIdx.x >> 6;
    const int l  = threadIdx.x & 63;
    const int i4 = wv * 64 + l;        // float4 column index, m = 4*i4..4*i4+3

    float4 sc = {0.f, 0.f, 0.f, 0.f};
    float4 tt = {0.f, 0.f, 0.f, 0.f};
    #pragma unroll
    for (int z = 0; z < 8; ++z) {
        const float4 s = ((const float4*)(ws + OFF_P + (size_t)z * PSZ + (size_t)n * NB))[i4];
        const float4 p = ((const float4*)(ws + OFF_P + (size_t)(8 + z) * PSZ + (size_t)n * NB))[i4];
        sc.x += s.x; sc.y += s.y; sc.z += s.z; sc.w += s.w;
        tt.x += p.x; tt.y += p.y; tt.z += p.z; tt.w += p.w;
    }

    const float invn = ws[OFF_INV + n];
    const float4 inv4 = *(const float4*)(ws + OFF_INV + 4 * i4);
    float4 cc;
    cc.x = sc.x * invn * inv4.x;
    cc.y = sc.y * invn * inv4.y;
    cc.z = sc.z * invn * inv4.z;
    cc.w = sc.w * invn * inv4.w;

    // deno over neg cols (waves 2,3 i.e. m >= 512)
    float ep = 0.f;
    if (wv >= 2)
        ep = __expf(cc.x) + __expf(cc.y) + __expf(cc.z) + __expf(cc.w);
    #pragma unroll
    for (int off = 32; off; off >>= 1) ep += __shfl_xor(ep, off);
    if (l == 0) eneg_s[wv] = ep;
    __syncthreads();
    const float eneg = eneg_s[2] + eneg_s[3];

    float part = 0.f;
    if (wv < 2) {   // pos cols: closs terms
        part += __logf(eneg + __expf(cc.x) + EPSV) - cc.x;
        part += __logf(eneg + __expf(cc.y) + EPSV) - cc.y;
        part += __logf(eneg + __expf(cc.z) + EPSV) - cc.z;
        part += __logf(eneg + __expf(cc.w) + EPSV) - cc.w;
    }

    // BCE
    const float t1n  = ws[OFF_T1 + n];
    const float bias = lb[0];
    const float4 t2 = *(const float4*)(ws + OFF_T2 + 4 * i4);
    float lgx = t1n + t2.x + tt.x + bias;
    float lgy = t1n + t2.y + tt.y + bias;
    float lgz = t1n + t2.z + tt.z + bias;
    float lgw = t1n + t2.w + tt.w + bias;
    float b;
    if (wv < 2)  // label 1
        b = softplus_f(-lgx) + softplus_f(-lgy) + softplus_f(-lgz) + softplus_f(-lgw);
    else         // label 0
        b = softplus_f(lgx) + softplus_f(lgy) + softplus_f(lgz) + softplus_f(lgw);
    part += b * (1.f / 1024.f);

    #pragma unroll
    for (int off = 32; off; off >>= 1) part += __shfl_xor(part, off);
    if (l == 0) red[wv] = part;
    __syncthreads();
    if (threadIdx.x == 0)
        atomicAdd(out, red[0] + red[1] + red[2] + red[3]);
}

extern "C" void kernel_launch(void* const* d_in, const int* in_sizes, int n_in,
                              void* d_out, int out_size, void* d_ws, size_t ws_size,
                              hipStream_t stream) {
    (void)in_sizes; (void)n_in; (void)out_size; (void)ws_size;
    const float* pos = (const float*)d_in[0];
    const float* neg = (const float*)d_in[1];
    const float* w   = (const float*)d_in[2];
    const float* lb  = (const float*)d_in[3];
    float* out = (float*)d_out;
    float* ws  = (float*)d_ws;

    prep_kernel<<<256, 256, 0, stream>>>(pos, neg, w, ws, out);
    fused_kernel<<<dim3(8, 4, 8), 256, 0, stream>>>(pos, neg, w, ws);
    finish_kernel<<<512, 256, 0, stream>>>(lb, ws, out);
}

// Round 6
// 110.743 us; speedup vs baseline: 1.0915x; 1.0915x over previous
//
#include <hip/hip_runtime.h>
#include <math.h>

#define NPOS 512
#define DIM  512
#define NB   1024
#define EPSV 1e-5f
#define COS_EPS 1e-8f

// ws float offsets
#define OFF_INV 0                      // [1024] inv norms, allv order [pos;neg]
#define OFF_T1  1024                   // [512]  pos . w1
#define OFF_T2  1536                   // [1024] allv . w2
#define OFF_S   2560                   // [512*1024] final cos matrix (cols = allv m)
#define PSZ     (NPOS * NB)            // 524288
#define OFF_TP  (OFF_S + PSZ)          // 8 x PSZ t3 partials (z = 0..7)
#define OFF_BF  (OFF_TP + 8 * PSZ)     // bf16 allv [1024*512] (as ushort, 1 MB)

// bank-spread swizzle for 128-wide k-major LDS tiles: 2-way max aliasing
#define FSW(x) ((x) + 4 * ((x) >> 5))

typedef __attribute__((ext_vector_type(8))) __bf16 bf16x8;
typedef __attribute__((ext_vector_type(4))) float  f32x4;

__device__ __forceinline__ float softplus_f(float x) {
    return fmaxf(x, 0.f) + __logf(1.f + __expf(-fabsf(x)));
}

__device__ __forceinline__ unsigned short f2bf(float f) {
    union { float f; unsigned int u; } v; v.f = f;
    unsigned int r = (v.u + 0x7fffu + ((v.u >> 16) & 1u)) >> 16;
    return (unsigned short)r;
}

// ---------------- Kernel 1: norms + t1 + t2 + bf16 convert + zero out ----------------
__global__ __launch_bounds__(256) void prep_kernel(
    const float* __restrict__ pos, const float* __restrict__ neg,
    const float* __restrict__ w, float* __restrict__ ws, float* __restrict__ out)
{
    int gtid = blockIdx.x * 256 + threadIdx.x;
    if (gtid == 0) out[0] = 0.f;
    int row  = gtid >> 6;     // one wave per row, 1024 rows (allv order)
    int lane = threadIdx.x & 63;
    if (row >= NB) return;
    bool is_pos = row < NPOS;
    const float* r = is_pos ? pos + row * DIM : neg + (row - NPOS) * DIM;

    const float4* r4  = (const float4*)r + lane * 2;
    const float4* w14 = (const float4*)(w) + lane * 2;
    const float4* w24 = (const float4*)(w + DIM) + lane * 2;
    float4 a0 = r4[0],  a1 = r4[1];
    float4 u0 = w14[0], u1 = w14[1];
    float4 v0 = w24[0], v1 = w24[1];

    // bf16 convert: lane owns elements [lane*8, lane*8+8)
    uint4 pk;
    pk.x = (unsigned)f2bf(a0.x) | ((unsigned)f2bf(a0.y) << 16);
    pk.y = (unsigned)f2bf(a0.z) | ((unsigned)f2bf(a0.w) << 16);
    pk.z = (unsigned)f2bf(a1.x) | ((unsigned)f2bf(a1.y) << 16);
    pk.w = (unsigned)f2bf(a1.z) | ((unsigned)f2bf(a1.w) << 16);
    ((uint4*)(ws + OFF_BF))[row * 64 + lane] = pk;

    float ss  = a0.x*a0.x + a0.y*a0.y + a0.z*a0.z + a0.w*a0.w
              + a1.x*a1.x + a1.y*a1.y + a1.z*a1.z + a1.w*a1.w;
    float dw1 = a0.x*u0.x + a0.y*u0.y + a0.z*u0.z + a0.w*u0.w
              + a1.x*u1.x + a1.y*u1.y + a1.z*u1.z + a1.w*u1.w;
    float dw2 = a0.x*v0.x + a0.y*v0.y + a0.z*v0.z + a0.w*v0.w
              + a1.x*v1.x + a1.y*v1.y + a1.z*v1.z + a1.w*v1.w;

    #pragma unroll
    for (int off = 32; off; off >>= 1) {
        ss  += __shfl_xor(ss, off);
        dw1 += __shfl_xor(dw1, off);
        dw2 += __shfl_xor(dw2, off);
    }
    if (lane == 0) {
        float inv = 1.f / fmaxf(sqrtf(ss), COS_EPS);
        ws[OFF_INV + row] = inv;
        ws[OFF_T2 + row]  = dw2;
        if (is_pos) ws[OFF_T1 + row] = dw1;
    }
}

// ---------------- Kernel 2: cos matrix via bf16 MFMA ----------------
// one wave per 16x16 output tile; 2048 waves = 512 blocks (2 blocks/CU).
// Layouts (HW-verified m89/m120/m74): A[m=lane&15][k=quad*8+j],
// B[k=quad*8+j][n=lane&15], D[col=lane&15][row=quad*4+reg].
__global__ __launch_bounds__(256) void cosmat_mfma(
    float* __restrict__ ws)
{
    const int wave = (blockIdx.x * 256 + threadIdx.x) >> 6;   // 0..2047
    const int lane = threadIdx.x & 63;
    const int n0 = (wave >> 6) << 4;    // pos-row tile
    const int m0 = (wave & 63) << 4;    // allv-row tile
    const int rc   = lane & 15;
    const int quad = lane >> 4;

    const unsigned short* bf = (const unsigned short*)(ws + OFF_BF);
    const bf16x8* pa = (const bf16x8*)(bf + (n0 + rc) * DIM + quad * 8);
    const bf16x8* pb = (const bf16x8*)(bf + (m0 + rc) * DIM + quad * 8);

    f32x4 acc = {0.f, 0.f, 0.f, 0.f};
    #pragma unroll
    for (int k = 0; k < 16; ++k)
        acc = __builtin_amdgcn_mfma_f32_16x16x32_bf16(pa[4 * k], pb[4 * k], acc, 0, 0, 0);

    float* S = ws + OFF_S;
    const float invm = ws[OFF_INV + m0 + rc];
    #pragma unroll
    for (int e = 0; e < 4; ++e) {
        int n = n0 + quad * 4 + e;
        S[(size_t)n * NB + m0 + rc] = acc[e] * ws[OFF_INV + n] * invm;
    }
}

// ---------------- Kernel 3: t3 = sum_d |pos - allv| * w3, k-split(8) ----------------
// 64n x 128m tile, k-major LDS (As[k][n], Bs[k][fm]), single barrier,
// per thread 4n x 8m. grid (8,8,8) = 512 blocks = 2 blocks/CU.
__global__ __launch_bounds__(256, 2) void t3_kernel(
    const float* __restrict__ pos, const float* __restrict__ neg,
    const float* __restrict__ w, float* __restrict__ ws)
{
    __shared__ __align__(16) float As[64][68];    // [k][n]   reads 2-way
    __shared__ __align__(16) float Bs[64][140];   // [k][FSW(m)] reads 2-way

    const int tid = threadIdx.x;
    const int m0 = blockIdx.x * 128;
    const int n0 = blockIdx.y * 64;
    const int kb = blockIdx.z * 64;

    const float* Asrc = pos + (size_t)n0 * DIM + kb;
    const float* Bsrc = ((m0 < NPOS) ? (pos + (size_t)m0 * DIM)
                                     : (neg + (size_t)(m0 - NPOS) * DIM)) + kb;
    const float* w3 = w + 2 * DIM + kb;

    // stage A: 64 rows x 64 k. thread: row r=tid>>2, k-group g=tid&3 (16 k each)
    {
        const int r = tid >> 2, g = (tid & 3) * 16;
        #pragma unroll
        for (int u = 0; u < 4; ++u) {
            float4 v = *(const float4*)(Asrc + (size_t)r * DIM + g + 4 * u);
            As[g + 4 * u + 0][r] = v.x;
            As[g + 4 * u + 1][r] = v.y;
            As[g + 4 * u + 2][r] = v.z;
            As[g + 4 * u + 3][r] = v.w;
        }
    }
    // stage B: 128 rows x 64 k. thread: row r=tid>>1, k-half h=(tid&1)*32
    {
        const int r = tid >> 1, h = (tid & 1) * 32;
        const int fr = FSW(r);
        #pragma unroll
        for (int u = 0; u < 8; ++u) {
            float4 v = *(const float4*)(Bsrc + (size_t)r * DIM + h + 4 * u);
            Bs[h + 4 * u + 0][fr] = v.x;
            Bs[h + 4 * u + 1][fr] = v.y;
            Bs[h + 4 * u + 2][fr] = v.z;
            Bs[h + 4 * u + 3][fr] = v.w;
        }
    }
    __syncthreads();

    const int n4 = (tid & 15) * 4;            // 4 consecutive n
    const int m8 = (tid >> 4) * 8;            // 8 consecutive m
    const int fm = FSW(m8);

    float acc[4][8] = {{0.f}};

    #pragma unroll 4
    for (int k = 0; k < 64; ++k) {
        const float4 av = *(const float4*)&As[k][n4];
        const float4 b0 = *(const float4*)&Bs[k][fm];
        const float4 b1 = *(const float4*)&Bs[k][fm + 4];
        const float wk = w3[k];               // wave-uniform -> scalar load
        const float a[4] = {av.x, av.y, av.z, av.w};
        const float b[8] = {b0.x, b0.y, b0.z, b0.w, b1.x, b1.y, b1.z, b1.w};
        #pragma unroll
        for (int r = 0; r < 4; ++r)
            #pragma unroll
            for (int s = 0; s < 8; ++s)
                acc[r][s] = fmaf(fabsf(a[r] - b[s]), wk, acc[r][s]);
    }

    float* Tp = ws + OFF_TP + (size_t)blockIdx.z * PSZ;
    #pragma unroll
    for (int r = 0; r < 4; ++r) {
        int n = n0 + n4 + r;
        float4 o0 = {acc[r][0], acc[r][1], acc[r][2], acc[r][3]};
        float4 o1 = {acc[r][4], acc[r][5], acc[r][6], acc[r][7]};
        *(float4*)(Tp + (size_t)n * NB + m0 + m8)     = o0;
        *(float4*)(Tp + (size_t)n * NB + m0 + m8 + 4) = o1;
    }
}

// ---------------- Kernel 4: combine + closs + BCE ----------------
// 512 blocks, one n-row per block; 4 waves split m (256 each).
// waves 2,3 own neg cols (deno); cross-wave eneg via LDS.
__global__ __launch_bounds__(256) void finish_kernel(
    const float* __restrict__ lb, const float* __restrict__ ws, float* __restrict__ out)
{
    __shared__ float eneg_s[4];
    __shared__ float red[4];

    const int n  = blockIdx.x;
    const int wv = threadIdx.x >> 6;
    const int l  = threadIdx.x & 63;
    const int i4 = wv * 64 + l;        // float4 column index, m = 4*i4..4*i4+3

    // cos values: already normalized in S
    const float4 cc = ((const float4*)(ws + OFF_S + (size_t)n * NB))[i4];

    // t3 = sum of 8 k-partials
    float4 tt = {0.f, 0.f, 0.f, 0.f};
    #pragma unroll
    for (int z = 0; z < 8; ++z) {
        const float4 p = ((const float4*)(ws + OFF_TP + (size_t)z * PSZ + (size_t)n * NB))[i4];
        tt.x += p.x; tt.y += p.y; tt.z += p.z; tt.w += p.w;
    }

    // deno over neg cols (waves 2,3 i.e. m >= 512)
    float ep = 0.f;
    if (wv >= 2)
        ep = __expf(cc.x) + __expf(cc.y) + __expf(cc.z) + __expf(cc.w);
    #pragma unroll
    for (int off = 32; off; off >>= 1) ep += __shfl_xor(ep, off);
    if (l == 0) eneg_s[wv] = ep;
    __syncthreads();
    const float eneg = eneg_s[2] + eneg_s[3];

    float part = 0.f;
    if (wv < 2) {   // pos cols: closs terms
        part += __logf(eneg + __expf(cc.x) + EPSV) - cc.x;
        part += __logf(eneg + __expf(cc.y) + EPSV) - cc.y;
        part += __logf(eneg + __expf(cc.z) + EPSV) - cc.z;
        part += __logf(eneg + __expf(cc.w) + EPSV) - cc.w;
    }

    // BCE
    const float t1n  = ws[OFF_T1 + n];
    const float bias = lb[0];
    const float4 t2 = *(const float4*)(ws + OFF_T2 + 4 * i4);
    float lgx = t1n + t2.x + tt.x + bias;
    float lgy = t1n + t2.y + tt.y + bias;
    float lgz = t1n + t2.z + tt.z + bias;
    float lgw = t1n + t2.w + tt.w + bias;
    float b;
    if (wv < 2)  // label 1
        b = softplus_f(-lgx) + softplus_f(-lgy) + softplus_f(-lgz) + softplus_f(-lgw);
    else         // label 0
        b = softplus_f(lgx) + softplus_f(lgy) + softplus_f(lgz) + softplus_f(lgw);
    part += b * (1.f / 1024.f);

    #pragma unroll
    for (int off = 32; off; off >>= 1) part += __shfl_xor(part, off);
    if (l == 0) red[wv] = part;
    __syncthreads();
    if (threadIdx.x == 0)
        atomicAdd(out, red[0] + red[1] + red[2] + red[3]);
}

extern "C" void kernel_launch(void* const* d_in, const int* in_sizes, int n_in,
                              void* d_out, int out_size, void* d_ws, size_t ws_size,
                              hipStream_t stream) {
    (void)in_sizes; (void)n_in; (void)out_size; (void)ws_size;
    const float* pos = (const float*)d_in[0];
    const float* neg = (const float*)d_in[1];
    const float* w   = (const float*)d_in[2];
    const float* lb  = (const float*)d_in[3];
    float* out = (float*)d_out;
    float* ws  = (float*)d_ws;

    prep_kernel<<<256, 256, 0, stream>>>(pos, neg, w, ws, out);
    cosmat_mfma<<<512, 256, 0, stream>>>(ws);
    t3_kernel<<<dim3(8, 8, 8), 256, 0, stream>>>(pos, neg, w, ws);
    finish_kernel<<<512, 256, 0, stream>>>(lb, ws, out);
}

// Round 7
// 107.839 us; speedup vs baseline: 1.1209x; 1.0269x over previous
//
#include <hip/hip_runtime.h>
#include <math.h>

#define NPOS 512
#define DIM  512
#define NB   1024
#define EPSV 1e-5f
#define COS_EPS 1e-8f

// ws float offsets
#define OFF_INV 0                      // [1024] inv norms, allv order [pos;neg]
#define OFF_T1  1024                   // [512]  pos . w1
#define OFF_T2  1536                   // [1024] allv . w2
#define OFF_S   2560                   // [512*1024] RAW cos dots (cols = allv m)
#define PSZ     (NPOS * NB)            // 524288
#define OFF_TP  (OFF_S + PSZ)          // 8 x PSZ t3 partials (z = 0..7)

// bank-spread swizzle for 128-wide k-major LDS tiles: 2-way max aliasing
#define FSW(x) ((x) + 4 * ((x) >> 5))

typedef __attribute__((ext_vector_type(8))) __bf16 bf16x8;
typedef __attribute__((ext_vector_type(4))) float  f32x4;

__device__ __forceinline__ float softplus_f(float x) {
    return fmaxf(x, 0.f) + __logf(1.f + __expf(-fabsf(x)));
}

__device__ __forceinline__ unsigned f2bf2(float lo, float hi) {
    // two RNE bf16 packed into one dword
    union { float f; unsigned u; } a, b; a.f = lo; b.f = hi;
    unsigned x = (a.u + 0x7fffu + ((a.u >> 16) & 1u)) >> 16;
    unsigned y = (b.u + 0x7fffu + ((b.u >> 16) & 1u)) >> 16;
    return x | (y << 16);
}

// =============== K1: heterogeneous mega-kernel, 1280 blocks ===============
// blocks [0,512):    t3 partials (64n x 128m tile, k-major LDS, k-split 8)
// blocks [512,1024): raw cos dots via bf16 MFMA (fp32->bf16 in-register)
// blocks [1024,1280): prep (inv norms, t1, t2) + zero out
__global__ __launch_bounds__(256) void mega_kernel(
    const float* __restrict__ pos, const float* __restrict__ neg,
    const float* __restrict__ w, float* __restrict__ ws, float* __restrict__ out)
{
    __shared__ __align__(16) float As[64][68];    // t3 path only
    __shared__ __align__(16) float Bs[64][140];

    const int b   = blockIdx.x;
    const int tid = threadIdx.x;

    if (b < 512) {
        // ---------------- t3 path ----------------
        const int z  = b >> 6;
        const int bb = b & 63;
        const int n0 = (bb >> 3) * 64;
        const int m0 = (bb & 7) * 128;
        const int kb = z * 64;

        const float* Asrc = pos + (size_t)n0 * DIM + kb;
        const float* Bsrc = ((m0 < NPOS) ? (pos + (size_t)m0 * DIM)
                                         : (neg + (size_t)(m0 - NPOS) * DIM)) + kb;
        const float* w3 = w + 2 * DIM + kb;

        // stage A: 64 rows x 64 k (k-major in LDS)
        {
            const int r = tid >> 2, g = (tid & 3) * 16;
            #pragma unroll
            for (int u = 0; u < 4; ++u) {
                float4 v = *(const float4*)(Asrc + (size_t)r * DIM + g + 4 * u);
                As[g + 4 * u + 0][r] = v.x;
                As[g + 4 * u + 1][r] = v.y;
                As[g + 4 * u + 2][r] = v.z;
                As[g + 4 * u + 3][r] = v.w;
            }
        }
        // stage B: 128 rows x 64 k
        {
            const int r = tid >> 1, h = (tid & 1) * 32;
            const int fr = FSW(r);
            #pragma unroll
            for (int u = 0; u < 8; ++u) {
                float4 v = *(const float4*)(Bsrc + (size_t)r * DIM + h + 4 * u);
                Bs[h + 4 * u + 0][fr] = v.x;
                Bs[h + 4 * u + 1][fr] = v.y;
                Bs[h + 4 * u + 2][fr] = v.z;
                Bs[h + 4 * u + 3][fr] = v.w;
            }
        }
        __syncthreads();

        const int n4 = (tid & 15) * 4;
        const int m8 = (tid >> 4) * 8;
        const int fm = FSW(m8);

        float acc[4][8] = {{0.f}};

        #pragma unroll 4
        for (int k = 0; k < 64; ++k) {
            const float4 av = *(const float4*)&As[k][n4];
            const float4 b0 = *(const float4*)&Bs[k][fm];
            const float4 b1 = *(const float4*)&Bs[k][fm + 4];
            const float wk = w3[k];               // uniform -> s_load
            const float a[4] = {av.x, av.y, av.z, av.w};
            const float bv[8] = {b0.x, b0.y, b0.z, b0.w, b1.x, b1.y, b1.z, b1.w};
            #pragma unroll
            for (int r = 0; r < 4; ++r)
                #pragma unroll
                for (int s = 0; s < 8; ++s)
                    acc[r][s] = fmaf(fabsf(a[r] - bv[s]), wk, acc[r][s]);
        }

        float* Tp = ws + OFF_TP + (size_t)z * PSZ;
        #pragma unroll
        for (int r = 0; r < 4; ++r) {
            int n = n0 + n4 + r;
            float4 o0 = {acc[r][0], acc[r][1], acc[r][2], acc[r][3]};
            float4 o1 = {acc[r][4], acc[r][5], acc[r][6], acc[r][7]};
            *(float4*)(Tp + (size_t)n * NB + m0 + m8)     = o0;
            *(float4*)(Tp + (size_t)n * NB + m0 + m8 + 4) = o1;
        }
    } else if (b < 1024) {
        // ---------------- cos-matrix MFMA path (raw dots) ----------------
        // one wave per 16x16 tile; fragment layouts HW-verified (m89/m120).
        const int wave = ((b - 512) << 2) | (tid >> 6);   // 0..2047
        const int lane = tid & 63;
        const int n0 = (wave >> 6) << 4;    // pos-row tile (0..31)
        const int m0 = (wave & 63) << 4;    // allv-row tile (0..63)
        const int rc   = lane & 15;
        const int quad = lane >> 4;

        const float* arow = pos + (size_t)(n0 + rc) * DIM + quad * 8;
        const float* brow = ((m0 < NPOS) ? (pos + (size_t)(m0 + rc) * DIM)
                                         : (neg + (size_t)(m0 - NPOS + rc) * DIM)) + quad * 8;

        f32x4 acc = {0.f, 0.f, 0.f, 0.f};
        #pragma unroll 4
        for (int k = 0; k < 16; ++k) {
            float4 a0 = *(const float4*)(arow + k * 32);
            float4 a1 = *(const float4*)(arow + k * 32 + 4);
            float4 b0 = *(const float4*)(brow + k * 32);
            float4 b1 = *(const float4*)(brow + k * 32 + 4);
            union { unsigned u[4]; bf16x8 v; } af, bf;
            af.u[0] = f2bf2(a0.x, a0.y); af.u[1] = f2bf2(a0.z, a0.w);
            af.u[2] = f2bf2(a1.x, a1.y); af.u[3] = f2bf2(a1.z, a1.w);
            bf.u[0] = f2bf2(b0.x, b0.y); bf.u[1] = f2bf2(b0.z, b0.w);
            bf.u[2] = f2bf2(b1.x, b1.y); bf.u[3] = f2bf2(b1.z, b1.w);
            acc = __builtin_amdgcn_mfma_f32_16x16x32_bf16(af.v, bf.v, acc, 0, 0, 0);
        }

        float* S = ws + OFF_S;
        #pragma unroll
        for (int e = 0; e < 4; ++e) {
            int n = n0 + quad * 4 + e;               // D: col=lane&15, row=quad*4+e
            S[(size_t)n * NB + m0 + rc] = acc[e];    // raw dot; normalized in finish
        }
    } else {
        // ---------------- prep path ----------------
        if (b == 1024 && tid == 0) out[0] = 0.f;
        int row  = ((b - 1024) << 2) | (tid >> 6);   // 0..1023, allv order
        int lane = tid & 63;
        bool is_pos = row < NPOS;
        const float* r = is_pos ? pos + (size_t)row * DIM : neg + (size_t)(row - NPOS) * DIM;

        const float4* r4  = (const float4*)r + lane * 2;
        const float4* w14 = (const float4*)(w) + lane * 2;
        const float4* w24 = (const float4*)(w + DIM) + lane * 2;
        float4 a0 = r4[0],  a1 = r4[1];
        float4 u0 = w14[0], u1 = w14[1];
        float4 v0 = w24[0], v1 = w24[1];

        float ss  = a0.x*a0.x + a0.y*a0.y + a0.z*a0.z + a0.w*a0.w
                  + a1.x*a1.x + a1.y*a1.y + a1.z*a1.z + a1.w*a1.w;
        float dw1 = a0.x*u0.x + a0.y*u0.y + a0.z*u0.z + a0.w*u0.w
                  + a1.x*u1.x + a1.y*u1.y + a1.z*u1.z + a1.w*u1.w;
        float dw2 = a0.x*v0.x + a0.y*v0.y + a0.z*v0.z + a0.w*v0.w
                  + a1.x*v1.x + a1.y*v1.y + a1.z*v1.z + a1.w*v1.w;

        #pragma unroll
        for (int off = 32; off; off >>= 1) {
            ss  += __shfl_xor(ss, off);
            dw1 += __shfl_xor(dw1, off);
            dw2 += __shfl_xor(dw2, off);
        }
        if (lane == 0) {
            float inv = 1.f / fmaxf(sqrtf(ss), COS_EPS);
            ws[OFF_INV + row] = inv;
            ws[OFF_T2 + row]  = dw2;
            if (is_pos) ws[OFF_T1 + row] = dw1;
        }
    }
}

// =============== K2: combine + closs + BCE ===============
// 512 blocks, one n-row per block; 4 waves split m (256 each).
// waves 2,3 own neg cols (deno); cross-wave eneg via LDS.
__global__ __launch_bounds__(256) void finish_kernel(
    const float* __restrict__ lb, const float* __restrict__ ws, float* __restrict__ out)
{
    __shared__ float eneg_s[4];
    __shared__ float red[4];

    const int n  = blockIdx.x;
    const int wv = threadIdx.x >> 6;
    const int l  = threadIdx.x & 63;
    const int i4 = wv * 64 + l;        // float4 column index, m = 4*i4..4*i4+3

    // raw dots -> normalized cos
    const float invn = ws[OFF_INV + n];
    const float4 sraw = ((const float4*)(ws + OFF_S + (size_t)n * NB))[i4];
    const float4 inv4 = *(const float4*)(ws + OFF_INV + 4 * i4);
    float4 cc;
    cc.x = sraw.x * invn * inv4.x;
    cc.y = sraw.y * invn * inv4.y;
    cc.z = sraw.z * invn * inv4.z;
    cc.w = sraw.w * invn * inv4.w;

    // t3 = sum of 8 k-partials
    float4 tt = {0.f, 0.f, 0.f, 0.f};
    #pragma unroll
    for (int z = 0; z < 8; ++z) {
        const float4 p = ((const float4*)(ws + OFF_TP + (size_t)z * PSZ + (size_t)n * NB))[i4];
        tt.x += p.x; tt.y += p.y; tt.z += p.z; tt.w += p.w;
    }

    // deno over neg cols (waves 2,3 i.e. m >= 512)
    float ep = 0.f;
    if (wv >= 2)
        ep = __expf(cc.x) + __expf(cc.y) + __expf(cc.z) + __expf(cc.w);
    #pragma unroll
    for (int off = 32; off; off >>= 1) ep += __shfl_xor(ep, off);
    if (l == 0) eneg_s[wv] = ep;
    __syncthreads();
    const float eneg = eneg_s[2] + eneg_s[3];

    float part = 0.f;
    if (wv < 2) {   // pos cols: closs terms
        part += __logf(eneg + __expf(cc.x) + EPSV) - cc.x;
        part += __logf(eneg + __expf(cc.y) + EPSV) - cc.y;
        part += __logf(eneg + __expf(cc.z) + EPSV) - cc.z;
        part += __logf(eneg + __expf(cc.w) + EPSV) - cc.w;
    }

    // BCE
    const float t1n  = ws[OFF_T1 + n];
    const float bias = lb[0];
    const float4 t2 = *(const float4*)(ws + OFF_T2 + 4 * i4);
    float lgx = t1n + t2.x + tt.x + bias;
    float lgy = t1n + t2.y + tt.y + bias;
    float lgz = t1n + t2.z + tt.z + bias;
    float lgw = t1n + t2.w + tt.w + bias;
    float bb;
    if (wv < 2)  // label 1
        bb = softplus_f(-lgx) + softplus_f(-lgy) + softplus_f(-lgz) + softplus_f(-lgw);
    else         // label 0
        bb = softplus_f(lgx) + softplus_f(lgy) + softplus_f(lgz) + softplus_f(lgw);
    part += bb * (1.f / 1024.f);

    #pragma unroll
    for (int off = 32; off; off >>= 1) part += __shfl_xor(part, off);
    if (l == 0) red[wv] = part;
    __syncthreads();
    if (threadIdx.x == 0)
        atomicAdd(out, red[0] + red[1] + red[2] + red[3]);
}

extern "C" void kernel_launch(void* const* d_in, const int* in_sizes, int n_in,
                              void* d_out, int out_size, void* d_ws, size_t ws_size,
                              hipStream_t stream) {
    (void)in_sizes; (void)n_in; (void)out_size; (void)ws_size;
    const float* pos = (const float*)d_in[0];
    const float* neg = (const float*)d_in[1];
    const float* w   = (const float*)d_in[2];
    const float* lb  = (const float*)d_in[3];
    float* out = (float*)d_out;
    float* ws  = (float*)d_ws;

    mega_kernel<<<1280, 256, 0, stream>>>(pos, neg, w, ws, out);
    finish_kernel<<<512, 256, 0, stream>>>(lb, ws, out);
}